// Round 3
// baseline (5348.586 us; speedup 1.0000x reference)
//
#include <hip/hip_runtime.h>
#include <hip/hip_bf16.h>

#define NN 100000
#define EE 500000

typedef __attribute__((ext_vector_type(8))) short bf16x8;
typedef __attribute__((ext_vector_type(4))) float f32x4;

__device__ inline unsigned short f2bf(float f) {
  union { float f; unsigned int u; } v; v.f = f;
  unsigned int r = v.u + 0x7FFFu + ((v.u >> 16) & 1u);
  return (unsigned short)(r >> 16);
}
__device__ inline float bf2f(unsigned short b) {
  union { unsigned int u; float f; } v; v.u = ((unsigned int)b) << 16;
  return v.f;
}
// split v into hi + lo bf16 (lo captures the residual)
__device__ inline void split_bf(float v, unsigned short& hi, unsigned short& lo) {
  hi = f2bf(v);
  lo = f2bf(v - bf2f(hi));
}

// ---------------- prep: W1 (L,128,256) -> W1T hi/lo bf16 [l][n][k]; W2 (L,256,128) -> W2T hi/lo [l][i][j]
__global__ __launch_bounds__(256) void prep_kernel(const float* __restrict__ W1,
                                                   const float* __restrict__ W2,
                                                   unsigned short* __restrict__ w1h,
                                                   unsigned short* __restrict__ w1l,
                                                   unsigned short* __restrict__ w2h,
                                                   unsigned short* __restrict__ w2l) {
  int gid = blockIdx.x * 256 + threadIdx.x;
  if (gid < 5 * 128 * 256) {
    int l = gid / 32768; int rem = gid % 32768;
    int k = rem / 256;   int n = rem % 256;
    unsigned short hi, lo;
    split_bf(W1[gid], hi, lo);
    w1h[l * 32768 + n * 128 + k] = hi;
    w1l[l * 32768 + n * 128 + k] = lo;
  } else if (gid < 2 * 5 * 128 * 256) {
    int g = gid - 163840;
    int l = g / 32768; int rem = g % 32768;
    int j = rem / 128; int i = rem % 128;
    unsigned short hi, lo;
    split_bf(W2[g], hi, lo);
    w2h[l * 32768 + i * 256 + j] = hi;
    w2l[l * 32768 + i * 256 + j] = lo;
  }
}

// ---------------- atom embedding: h[n,d] = sum_f atom_emb[f, x[n,f], d]; agg = (1+eps0)*h
__global__ __launch_bounds__(256) void atom_kernel(const int* __restrict__ x,
                                                   const float* __restrict__ aemb,
                                                   const float* __restrict__ eps,
                                                   float* __restrict__ h,
                                                   float* __restrict__ agg) {
  int gid = blockIdx.x * 256 + threadIdx.x;
  int n = gid >> 5, qq = gid & 31;
  if (n >= NN) return;
  float4 s = {0.f, 0.f, 0.f, 0.f};
#pragma unroll
  for (int f = 0; f < 9; ++f) {
    int xi = x[n * 9 + f];
    float4 v = *(const float4*)(aemb + (f * 120 + xi) * 128 + qq * 4);
    s.x += v.x; s.y += v.y; s.z += v.z; s.w += v.w;
  }
  *(float4*)(h + (long)n * 128 + qq * 4) = s;
  float e = 1.f + eps[0];
  float4 a = {s.x * e, s.y * e, s.z * e, s.w * e};
  *(float4*)(agg + (long)n * 128 + qq * 4) = a;
}

// ---------------- edge: agg[dst] += relu(h[src] + bond_e) * ew
__global__ __launch_bounds__(256) void edge_kernel(const int* __restrict__ ei,
                                                   const int* __restrict__ ea,
                                                   const float* __restrict__ ew,
                                                   const float* __restrict__ bemb, // + l*3072
                                                   const float* __restrict__ h,
                                                   float* __restrict__ agg) {
  int gid = blockIdx.x * 256 + threadIdx.x;
  int e = gid >> 5, qq = gid & 31;
  if (e >= EE) return;
  int src = ei[e], dst = ei[EE + e];
  float w = ew[e];
  int a0 = ea[e * 3 + 0], a1 = ea[e * 3 + 1], a2 = ea[e * 3 + 2];
  float4 b0 = *(const float4*)(bemb + (0 * 8 + a0) * 128 + qq * 4);
  float4 b1 = *(const float4*)(bemb + (1 * 8 + a1) * 128 + qq * 4);
  float4 b2 = *(const float4*)(bemb + (2 * 8 + a2) * 128 + qq * 4);
  float4 hv = *(const float4*)(h + (long)src * 128 + qq * 4);
  float4 mm;
  mm.x = fmaxf(hv.x + b0.x + b1.x + b2.x, 0.f) * w;
  mm.y = fmaxf(hv.y + b0.y + b1.y + b2.y, 0.f) * w;
  mm.z = fmaxf(hv.z + b0.z + b1.z + b2.z, 0.f) * w;
  mm.w = fmaxf(hv.w + b0.w + b1.w + b2.w, 0.f) * w;
  float* dp = agg + (long)dst * 128 + qq * 4;
  unsafeAtomicAdd(dp + 0, mm.x);
  unsafeAtomicAdd(dp + 1, mm.y);
  unsafeAtomicAdd(dp + 2, mm.z);
  unsafeAtomicAdd(dp + 3, mm.w);
}

// ---------------- zero stats (1536 floats)
__global__ void zero_kernel(float* __restrict__ p) {
  for (int i = threadIdx.x; i < 1536; i += 256) p[i] = 0.f;
}

// ---------------- GEMM1: t1 = z @ W1 (split-bf16, fp32-accurate); z (N,128) f32; out t1 bf16 (N,256) + col stats (from f32 acc)
__global__ __launch_bounds__(256) void gemm1_kernel(const float* __restrict__ z,
                                                    const unsigned short* __restrict__ w1h, // layer base
                                                    const unsigned short* __restrict__ w1l,
                                                    unsigned short* __restrict__ t1b,
                                                    float* __restrict__ sum1,
                                                    float* __restrict__ sq1) {
  __shared__ unsigned short Ahi[128 * 36];
  __shared__ unsigned short Alo[128 * 36];
  __shared__ unsigned short Bhi[128 * 36];
  __shared__ unsigned short Blo[128 * 36];
  const int tid = threadIdx.x;
  const int rbase = blockIdx.x * 128;
  const int cb = blockIdx.y; // 0..1 -> 128-col half
  const int w = tid >> 6, lane = tid & 63;
  const int wr = w >> 1, wc = w & 1;
  const int m = lane & 15, q = lane >> 4;
  f32x4 acc[4][4];
  const f32x4 z4 = {0.f, 0.f, 0.f, 0.f};
#pragma unroll
  for (int a = 0; a < 4; ++a)
#pragma unroll
    for (int b = 0; b < 4; ++b) acc[a][b] = z4;

  for (int kc = 0; kc < 4; ++kc) { // K = 128 in chunks of 32
    if (kc) __syncthreads();
    { // stage A: 128 rows x 32 k (f32 -> hi/lo bf16)
      int c4 = tid & 7, r0 = tid >> 3;
#pragma unroll
      for (int i = 0; i < 4; ++i) {
        int r = r0 + i * 32;
        int gr = rbase + r;
        float4 v = {0.f, 0.f, 0.f, 0.f};
        if (gr < NN) v = *(const float4*)(z + (long)gr * 128 + kc * 32 + c4 * 4);
        ushort4 h4, l4;
        split_bf(v.x, h4.x, l4.x); split_bf(v.y, h4.y, l4.y);
        split_bf(v.z, h4.z, l4.z); split_bf(v.w, h4.w, l4.w);
        *(ushort4*)(Ahi + r * 36 + c4 * 4) = h4;
        *(ushort4*)(Alo + r * 36 + c4 * 4) = l4;
      }
      // stage B: 128 cols x 32 k (bf16 hi/lo straight copy)
      int u = tid & 3, r0b = tid >> 2;
#pragma unroll
      for (int i = 0; i < 2; ++i) {
        int r = r0b + i * 64;
        uint4 vh = *(const uint4*)(w1h + ((cb * 128 + r) * 128 + kc * 32 + u * 8));
        uint4 vl = *(const uint4*)(w1l + ((cb * 128 + r) * 128 + kc * 32 + u * 8));
        *(uint4*)(Bhi + r * 36 + u * 8) = vh;
        *(uint4*)(Blo + r * 36 + u * 8) = vl;
      }
    }
    __syncthreads();
    bf16x8 ah[4], al[4], bh[4], bl[4];
#pragma unroll
    for (int rt = 0; rt < 4; ++rt) {
      ah[rt] = *(const bf16x8*)(Ahi + (wr * 64 + rt * 16 + m) * 36 + q * 8);
      al[rt] = *(const bf16x8*)(Alo + (wr * 64 + rt * 16 + m) * 36 + q * 8);
    }
#pragma unroll
    for (int ct = 0; ct < 4; ++ct) {
      bh[ct] = *(const bf16x8*)(Bhi + (wc * 64 + ct * 16 + m) * 36 + q * 8);
      bl[ct] = *(const bf16x8*)(Blo + (wc * 64 + ct * 16 + m) * 36 + q * 8);
    }
#pragma unroll
    for (int rt = 0; rt < 4; ++rt)
#pragma unroll
      for (int ct = 0; ct < 4; ++ct) {
        acc[rt][ct] = __builtin_amdgcn_mfma_f32_16x16x32_bf16(ah[rt], bh[ct], acc[rt][ct], 0, 0, 0);
        acc[rt][ct] = __builtin_amdgcn_mfma_f32_16x16x32_bf16(al[rt], bh[ct], acc[rt][ct], 0, 0, 0);
        acc[rt][ct] = __builtin_amdgcn_mfma_f32_16x16x32_bf16(ah[rt], bl[ct], acc[rt][ct], 0, 0, 0);
      }
  }
  // epilogue: store bf16 + column stats from f32 acc
#pragma unroll
  for (int ct = 0; ct < 4; ++ct) {
    int gc = cb * 128 + wc * 64 + ct * 16 + m;
    float s = 0.f, s2 = 0.f;
#pragma unroll
    for (int rt = 0; rt < 4; ++rt) {
      int grow = rbase + wr * 64 + rt * 16 + q * 4;
#pragma unroll
      for (int i = 0; i < 4; ++i) {
        float v = acc[rt][ct][i];
        s += v; s2 += v * v;
        if (grow + i < NN) t1b[(long)(grow + i) * 256 + gc] = f2bf(v);
      }
    }
    s  += __shfl_xor(s, 16);  s  += __shfl_xor(s, 32);
    s2 += __shfl_xor(s2, 16); s2 += __shfl_xor(s2, 32);
    if (q == 0) { unsafeAtomicAdd(&sum1[gc], s); unsafeAtomicAdd(&sq1[gc], s2); }
  }
}

// ---------------- stats: scale = g*rsqrt(var+eps), shift = bt - mu*scale
__global__ void stats_kernel(const float* __restrict__ sum, const float* __restrict__ sq,
                             const float* __restrict__ g, const float* __restrict__ bt,
                             float* __restrict__ scale, float* __restrict__ shift, int C) {
  int j = blockIdx.x * blockDim.x + threadIdx.x;
  if (j >= C) return;
  float mu = sum[j] * (1.f / NN);
  float var = sq[j] * (1.f / NN) - mu * mu;
  var = fmaxf(var, 0.f);
  float is = rsqrtf(var + 1e-5f);
  float sc = g[j] * is;
  scale[j] = sc;
  shift[j] = bt[j] - mu * sc;
}

// ---------------- GEMM2: t2 = relu(BN1(t1)) @ W2 (split-bf16); t1 bf16 (N,256); out t2 f32 (N,128) + stats
// NOTE: t2 (f32, 512B/row) overlays t1b (bf16, 512B/row) — same row extent. Within a block all
// t1b reads complete before the final __syncthreads; t2 writes happen after; blocks own disjoint
// rows. No __restrict__ on the aliasing pair.
__global__ __launch_bounds__(256) void gemm2_kernel(const unsigned short* t1b,
                                                    const float* __restrict__ scale1,
                                                    const float* __restrict__ shift1,
                                                    const unsigned short* __restrict__ w2h, // layer base
                                                    const unsigned short* __restrict__ w2l,
                                                    float* t2,
                                                    float* __restrict__ sum2,
                                                    float* __restrict__ sq2) {
  __shared__ unsigned short Ahi[128 * 36];
  __shared__ unsigned short Alo[128 * 36];
  __shared__ unsigned short Bhi[128 * 36];
  __shared__ unsigned short Blo[128 * 36];
  const int tid = threadIdx.x;
  const int rbase = blockIdx.x * 128;
  const int w = tid >> 6, lane = tid & 63;
  const int wr = w >> 1, wc = w & 1;
  const int m = lane & 15, q = lane >> 4;
  f32x4 acc[4][4];
  const f32x4 z4 = {0.f, 0.f, 0.f, 0.f};
#pragma unroll
  for (int a = 0; a < 4; ++a)
#pragma unroll
    for (int b = 0; b < 4; ++b) acc[a][b] = z4;

  for (int kc = 0; kc < 8; ++kc) { // K = 256 in chunks of 32
    if (kc) __syncthreads();
    {
      int u4 = tid & 3, r0 = tid >> 2;
      int j0 = kc * 32 + u4 * 8;
      float4 sc0 = *(const float4*)(scale1 + j0);
      float4 sc1 = *(const float4*)(scale1 + j0 + 4);
      float4 sh0 = *(const float4*)(shift1 + j0);
      float4 sh1 = *(const float4*)(shift1 + j0 + 4);
      // stage A: 128 rows x 32 j, val = relu(scale*bf2f(t1)+shift) -> hi/lo bf16
#pragma unroll
      for (int i = 0; i < 2; ++i) {
        int r = r0 + i * 64;
        int gr = rbase + r;
        ushort4 h0 = {0, 0, 0, 0}, l0 = {0, 0, 0, 0};
        ushort4 h1 = {0, 0, 0, 0}, l1 = {0, 0, 0, 0};
        if (gr < NN) {
          const unsigned short* srcp = t1b + (long)gr * 256 + j0;
          ushort4 u0 = *(const ushort4*)(srcp);
          ushort4 u1 = *(const ushort4*)(srcp + 4);
          float a0 = fmaxf(bf2f(u0.x) * sc0.x + sh0.x, 0.f);
          float a1 = fmaxf(bf2f(u0.y) * sc0.y + sh0.y, 0.f);
          float a2 = fmaxf(bf2f(u0.z) * sc0.z + sh0.z, 0.f);
          float a3 = fmaxf(bf2f(u0.w) * sc0.w + sh0.w, 0.f);
          float a4 = fmaxf(bf2f(u1.x) * sc1.x + sh1.x, 0.f);
          float a5 = fmaxf(bf2f(u1.y) * sc1.y + sh1.y, 0.f);
          float a6 = fmaxf(bf2f(u1.z) * sc1.z + sh1.z, 0.f);
          float a7 = fmaxf(bf2f(u1.w) * sc1.w + sh1.w, 0.f);
          split_bf(a0, h0.x, l0.x); split_bf(a1, h0.y, l0.y);
          split_bf(a2, h0.z, l0.z); split_bf(a3, h0.w, l0.w);
          split_bf(a4, h1.x, l1.x); split_bf(a5, h1.y, l1.y);
          split_bf(a6, h1.z, l1.z); split_bf(a7, h1.w, l1.w);
        }
        *(ushort4*)(Ahi + r * 36 + u4 * 8) = h0;
        *(ushort4*)(Ahi + r * 36 + u4 * 8 + 4) = h1;
        *(ushort4*)(Alo + r * 36 + u4 * 8) = l0;
        *(ushort4*)(Alo + r * 36 + u4 * 8 + 4) = l1;
      }
      // stage B: 128 cols x 32 k
      int u = tid & 3, r0b = tid >> 2;
#pragma unroll
      for (int i = 0; i < 2; ++i) {
        int r = r0b + i * 64;
        uint4 vh = *(const uint4*)(w2h + (r * 256 + kc * 32 + u * 8));
        uint4 vl = *(const uint4*)(w2l + (r * 256 + kc * 32 + u * 8));
        *(uint4*)(Bhi + r * 36 + u * 8) = vh;
        *(uint4*)(Blo + r * 36 + u * 8) = vl;
      }
    }
    __syncthreads();
    bf16x8 ah[4], al[4], bh[4], bl[4];
#pragma unroll
    for (int rt = 0; rt < 4; ++rt) {
      ah[rt] = *(const bf16x8*)(Ahi + (wr * 64 + rt * 16 + m) * 36 + q * 8);
      al[rt] = *(const bf16x8*)(Alo + (wr * 64 + rt * 16 + m) * 36 + q * 8);
    }
#pragma unroll
    for (int ct = 0; ct < 4; ++ct) {
      bh[ct] = *(const bf16x8*)(Bhi + (wc * 64 + ct * 16 + m) * 36 + q * 8);
      bl[ct] = *(const bf16x8*)(Blo + (wc * 64 + ct * 16 + m) * 36 + q * 8);
    }
#pragma unroll
    for (int rt = 0; rt < 4; ++rt)
#pragma unroll
      for (int ct = 0; ct < 4; ++ct) {
        acc[rt][ct] = __builtin_amdgcn_mfma_f32_16x16x32_bf16(ah[rt], bh[ct], acc[rt][ct], 0, 0, 0);
        acc[rt][ct] = __builtin_amdgcn_mfma_f32_16x16x32_bf16(al[rt], bh[ct], acc[rt][ct], 0, 0, 0);
        acc[rt][ct] = __builtin_amdgcn_mfma_f32_16x16x32_bf16(ah[rt], bl[ct], acc[rt][ct], 0, 0, 0);
      }
  }
#pragma unroll
  for (int ct = 0; ct < 4; ++ct) {
    int gc = wc * 64 + ct * 16 + m;
    float s = 0.f, s2 = 0.f;
#pragma unroll
    for (int rt = 0; rt < 4; ++rt) {
      int grow = rbase + wr * 64 + rt * 16 + q * 4;
#pragma unroll
      for (int i = 0; i < 4; ++i) {
        float v = acc[rt][ct][i];
        s += v; s2 += v * v;
        if (grow + i < NN) t2[(long)(grow + i) * 128 + gc] = v;
      }
    }
    s  += __shfl_xor(s, 16);  s  += __shfl_xor(s, 32);
    s2 += __shfl_xor(s2, 16); s2 += __shfl_xor(s2, 32);
    if (q == 0) { unsafeAtomicAdd(&sum2[gc], s); unsafeAtomicAdd(&sq2[gc], s2); }
  }
}

// ---------------- apply: y = BN2(t2); h = relu(y) (or y if last); agg = (1+eps[l+1])*relu(y)
__global__ __launch_bounds__(256) void apply_kernel(const float* __restrict__ t2,
                                                    const float* __restrict__ scale2,
                                                    const float* __restrict__ shift2,
                                                    const float* __restrict__ eps,
                                                    int lnext, int last,
                                                    float* __restrict__ h,
                                                    float* __restrict__ agg) {
  int gid = blockIdx.x * 256 + threadIdx.x;
  int n = gid >> 5, qq = gid & 31;
  if (n >= NN) return;
  float4 u = *(const float4*)(t2 + (long)n * 128 + qq * 4);
  float4 sc = *(const float4*)(scale2 + qq * 4);
  float4 sh = *(const float4*)(shift2 + qq * 4);
  float4 y;
  y.x = u.x * sc.x + sh.x;
  y.y = u.y * sc.y + sh.y;
  y.z = u.z * sc.z + sh.z;
  y.w = u.w * sc.w + sh.w;
  if (last) {
    *(float4*)(h + (long)n * 128 + qq * 4) = y;
  } else {
    float4 r;
    r.x = fmaxf(y.x, 0.f); r.y = fmaxf(y.y, 0.f);
    r.z = fmaxf(y.z, 0.f); r.w = fmaxf(y.w, 0.f);
    *(float4*)(h + (long)n * 128 + qq * 4) = r;
    float e = 1.f + eps[lnext];
    float4 a = {r.x * e, r.y * e, r.z * e, r.w * e};
    *(float4*)(agg + (long)n * 128 + qq * 4) = a;
  }
}

extern "C" void kernel_launch(void* const* d_in, const int* in_sizes, int n_in,
                              void* d_out, int out_size, void* d_ws, size_t ws_size,
                              hipStream_t stream) {
  (void)in_sizes; (void)n_in; (void)out_size; (void)ws_size;
  const int*   x      = (const int*)d_in[0];
  const int*   ei     = (const int*)d_in[1];
  const int*   ea     = (const int*)d_in[2];
  const float* ew     = (const float*)d_in[3];
  const float* aemb   = (const float*)d_in[4];
  const float* bemb   = (const float*)d_in[5];
  const float* eps    = (const float*)d_in[6];
  const float* W1     = (const float*)d_in[7];
  const float* g1     = (const float*)d_in[9];
  const float* bt1    = (const float*)d_in[10];
  const float* W2     = (const float*)d_in[11];
  const float* g_out  = (const float*)d_in[13];
  const float* bt_out = (const float*)d_in[14];

  float* h = (float*)d_out; // (N,128) f32, reused as h across layers

  // Compact ws layout — total 103,716,864 bytes:
  //   [0, 51.2M)        agg   (N,128) f32
  //   [51.2M, 102.4M)   t1    (N,256) bf16  -- overlaid by t2 (N,128) f32 (same 512B/row)
  //   [102.4M, ~103.7M) weights hi/lo bf16 + stats
  char* ws = (char*)d_ws;
  float*          agg = (float*)(ws);
  unsigned short* t1b = (unsigned short*)(ws + 51200000);
  float*          t2  = (float*)(ws + 51200000);
  unsigned short* w1h = (unsigned short*)(ws + 102400000);
  unsigned short* w1l = (unsigned short*)(ws + 102727680);
  unsigned short* w2h = (unsigned short*)(ws + 103055360);
  unsigned short* w2l = (unsigned short*)(ws + 103383040);
  float* stats = (float*)(ws + 103710720); // 1536 f32
  float* sum1 = stats;          float* sq1 = stats + 256;
  float* scale1 = stats + 512;  float* shift1 = stats + 768;
  float* sum2 = stats + 1024;   float* sq2 = stats + 1152;
  float* scale2 = stats + 1280; float* shift2 = stats + 1408;

  prep_kernel<<<1280, 256, 0, stream>>>(W1, W2, w1h, w1l, w2h, w2l);
  atom_kernel<<<12500, 256, 0, stream>>>(x, aemb, eps, h, agg);

  for (int l = 0; l < 5; ++l) {
    zero_kernel<<<1, 256, 0, stream>>>(stats);
    edge_kernel<<<62500, 256, 0, stream>>>(ei, ea, ew, bemb + l * 3072, h, agg);
    gemm1_kernel<<<dim3(782, 2), 256, 0, stream>>>(agg, w1h + l * 32768, w1l + l * 32768, t1b, sum1, sq1);
    stats_kernel<<<1, 256, 0, stream>>>(sum1, sq1, g1 + l * 256, bt1 + l * 256, scale1, shift1, 256);
    gemm2_kernel<<<782, 256, 0, stream>>>(t1b, scale1, shift1, w2h + l * 32768, w2l + l * 32768, t2, sum2, sq2);
    stats_kernel<<<1, 128, 0, stream>>>(sum2, sq2, g_out + l * 128, bt_out + l * 128, scale2, shift2, 128);
    apply_kernel<<<12500, 256, 0, stream>>>(t2, scale2, shift2, eps,
                                            (l + 1 < 5) ? (l + 1) : 4, (l == 4) ? 1 : 0, h, agg);
  }
}

// Round 4
// 1473.906 us; speedup vs baseline: 3.6289x; 3.6289x over previous
//
#include <hip/hip_runtime.h>
#include <hip/hip_bf16.h>

#define NN 100000
#define EE 500000

typedef __attribute__((ext_vector_type(8))) short bf16x8;
typedef __attribute__((ext_vector_type(4))) float f32x4;

__device__ inline unsigned short f2bf(float f) {
  union { float f; unsigned int u; } v; v.f = f;
  unsigned int r = v.u + 0x7FFFu + ((v.u >> 16) & 1u);
  return (unsigned short)(r >> 16);
}
__device__ inline float bf2f(unsigned short b) {
  union { unsigned int u; float f; } v; v.u = ((unsigned int)b) << 16;
  return v.f;
}
__device__ inline void split_bf(float v, unsigned short& hi, unsigned short& lo) {
  hi = f2bf(v);
  lo = f2bf(v - bf2f(hi));
}

// ---------------- prep: W1 (L,128,256) -> W1T hi/lo bf16 [l][n][k]; W2 (L,256,128) -> W2T hi/lo [l][i][j]
__global__ __launch_bounds__(256) void prep_kernel(const float* __restrict__ W1,
                                                   const float* __restrict__ W2,
                                                   unsigned short* __restrict__ w1h,
                                                   unsigned short* __restrict__ w1l,
                                                   unsigned short* __restrict__ w2h,
                                                   unsigned short* __restrict__ w2l) {
  int gid = blockIdx.x * 256 + threadIdx.x;
  if (gid < 5 * 128 * 256) {
    int l = gid / 32768; int rem = gid % 32768;
    int k = rem / 256;   int n = rem % 256;
    unsigned short hi, lo;
    split_bf(W1[gid], hi, lo);
    w1h[l * 32768 + n * 128 + k] = hi;
    w1l[l * 32768 + n * 128 + k] = lo;
  } else if (gid < 2 * 5 * 128 * 256) {
    int g = gid - 163840;
    int l = g / 32768; int rem = g % 32768;
    int j = rem / 128; int i = rem % 128;
    unsigned short hi, lo;
    split_bf(W2[g], hi, lo);
    w2h[l * 32768 + i * 256 + j] = hi;
    w2l[l * 32768 + i * 256 + j] = lo;
  }
}

// ---------------- CSR build: zero deg ----------------
__global__ __launch_bounds__(256) void zero_deg_kernel(int* __restrict__ deg) {
  int i = blockIdx.x * 256 + threadIdx.x;
  if (i < NN) deg[i] = 0;
}

// ---------------- histogram of dst ----------------
__global__ __launch_bounds__(256) void hist_kernel(const int* __restrict__ ei, int* __restrict__ deg) {
  int e = blockIdx.x * 256 + threadIdx.x;
  if (e < EE) atomicAdd(&deg[ei[EE + e]], 1);
}

// ---------------- scan stage 1: per-block (1024 elems) exclusive scan ----------------
__global__ __launch_bounds__(256) void scan1_kernel(const int* __restrict__ deg,
                                                    int* __restrict__ offs,
                                                    int* __restrict__ bsum) {
  __shared__ int sh[256];
  int b = blockIdx.x, t = threadIdx.x;
  int base = b * 1024 + t * 4;
  int v[4];
  int s = 0;
#pragma unroll
  for (int i = 0; i < 4; ++i) { v[i] = (base + i < NN) ? deg[base + i] : 0; s += v[i]; }
  sh[t] = s;
  __syncthreads();
  for (int off = 1; off < 256; off <<= 1) {
    int x = (t >= off) ? sh[t - off] : 0;
    __syncthreads();
    sh[t] += x;
    __syncthreads();
  }
  int excl = sh[t] - s;
  if (t == 255) bsum[b] = sh[255];
  int run = excl;
#pragma unroll
  for (int i = 0; i < 4; ++i) {
    if (base + i < NN) offs[base + i] = run;
    run += v[i];
  }
}

// ---------------- scan stage 2: exclusive scan of 98 block sums (single thread) ----------------
__global__ void scan2_kernel(int* __restrict__ bsum, int nb) {
  if (threadIdx.x == 0 && blockIdx.x == 0) {
    int run = 0;
    for (int i = 0; i < nb; ++i) { int v = bsum[i]; bsum[i] = run; run += v; }
  }
}

// ---------------- scan stage 3: add block offset; init cursor; offs[NN]=EE ----------------
__global__ __launch_bounds__(256) void scan3_kernel(int* __restrict__ offs,
                                                    const int* __restrict__ bsum,
                                                    int* __restrict__ cursor) {
  int i = blockIdx.x * 256 + threadIdx.x;
  if (i < NN) {
    int v = offs[i] + bsum[i >> 10];
    offs[i] = v;
    cursor[i] = v;
  } else if (i == NN) {
    offs[NN] = EE;
  }
}

// ---------------- scatter: sorted-by-dst packed edge data ----------------
// pk = src(17b) | a0<<17 | a1<<20 | a2<<23 ; wsrt = edge weight
__global__ __launch_bounds__(256) void scatter_kernel(const int* __restrict__ ei,
                                                      const int* __restrict__ ea,
                                                      const float* __restrict__ ew,
                                                      int* __restrict__ cursor,
                                                      int* __restrict__ pk,
                                                      float* __restrict__ wsrt) {
  int e = blockIdx.x * 256 + threadIdx.x;
  if (e >= EE) return;
  int dst = ei[EE + e];
  int pos = atomicAdd(&cursor[dst], 1);
  int src = ei[e];
  int a0 = ea[e * 3 + 0], a1 = ea[e * 3 + 1], a2 = ea[e * 3 + 2];
  pk[pos] = src | (a0 << 17) | (a1 << 20) | (a2 << 23);
  wsrt[pos] = ew[e];
}

// ---------------- atom embedding: h[n,d] = sum_f atom_emb[f, x[n,f], d] ----------------
__global__ __launch_bounds__(256) void atom_kernel(const int* __restrict__ x,
                                                   const float* __restrict__ aemb,
                                                   float* __restrict__ h) {
  int gid = blockIdx.x * 256 + threadIdx.x;
  int n = gid >> 5, qq = gid & 31;
  if (n >= NN) return;
  float4 s = {0.f, 0.f, 0.f, 0.f};
#pragma unroll
  for (int f = 0; f < 9; ++f) {
    int xi = x[n * 9 + f];
    float4 v = *(const float4*)(aemb + (f * 120 + xi) * 128 + qq * 4);
    s.x += v.x; s.y += v.y; s.z += v.z; s.w += v.w;
  }
  *(float4*)(h + (long)n * 128 + qq * 4) = s;
}

// ---------------- edge aggregate (CSR, no atomics):
// agg[n] = (1+eps[l])*h[n] + sum_{e in seg(n)} relu(h[src_e] + bond_e)*w_e
__global__ __launch_bounds__(256) void edge_agg_kernel(const int* __restrict__ offs,
                                                       const int* __restrict__ pk,
                                                       const float* __restrict__ wsrt,
                                                       const float* __restrict__ bemb, // + l*3072
                                                       const float* __restrict__ eps, int l,
                                                       const float* __restrict__ h,
                                                       float* __restrict__ agg) {
  int gid = blockIdx.x * 256 + threadIdx.x;
  int n = gid >> 5, qq = gid & 31;
  if (n >= NN) return;
  int s0 = offs[n], s1 = offs[n + 1];
  float e1 = 1.f + eps[l];
  float4 hn = *(const float4*)(h + (long)n * 128 + qq * 4);
  float4 acc = {hn.x * e1, hn.y * e1, hn.z * e1, hn.w * e1};
  for (int e = s0; e < s1; ++e) {
    int p = pk[e];
    float w = wsrt[e];
    int src = p & 131071;
    float4 b0 = *(const float4*)(bemb + (((p >> 17) & 7)) * 128 + qq * 4);
    float4 b1 = *(const float4*)(bemb + (8 + ((p >> 20) & 7)) * 128 + qq * 4);
    float4 b2 = *(const float4*)(bemb + (16 + ((p >> 23) & 7)) * 128 + qq * 4);
    float4 hv = *(const float4*)(h + (long)src * 128 + qq * 4);
    acc.x += fmaxf(hv.x + b0.x + b1.x + b2.x, 0.f) * w;
    acc.y += fmaxf(hv.y + b0.y + b1.y + b2.y, 0.f) * w;
    acc.z += fmaxf(hv.z + b0.z + b1.z + b2.z, 0.f) * w;
    acc.w += fmaxf(hv.w + b0.w + b1.w + b2.w, 0.f) * w;
  }
  *(float4*)(agg + (long)n * 128 + qq * 4) = acc;
}

// ---------------- zero stats (1536 floats)
__global__ void zero_kernel(float* __restrict__ p) {
  for (int i = threadIdx.x; i < 1536; i += 256) p[i] = 0.f;
}

// ---------------- GEMM1: t1 = z @ W1 (split-bf16, fp32-accurate); z (N,128) f32; out t1 bf16 (N,256) + col stats
__global__ __launch_bounds__(256) void gemm1_kernel(const float* __restrict__ z,
                                                    const unsigned short* __restrict__ w1h,
                                                    const unsigned short* __restrict__ w1l,
                                                    unsigned short* __restrict__ t1b,
                                                    float* __restrict__ sum1,
                                                    float* __restrict__ sq1) {
  __shared__ unsigned short Ahi[128 * 36];
  __shared__ unsigned short Alo[128 * 36];
  __shared__ unsigned short Bhi[128 * 36];
  __shared__ unsigned short Blo[128 * 36];
  const int tid = threadIdx.x;
  const int rbase = blockIdx.x * 128;
  const int cb = blockIdx.y;
  const int w = tid >> 6, lane = tid & 63;
  const int wr = w >> 1, wc = w & 1;
  const int m = lane & 15, q = lane >> 4;
  f32x4 acc[4][4];
  const f32x4 z4 = {0.f, 0.f, 0.f, 0.f};
#pragma unroll
  for (int a = 0; a < 4; ++a)
#pragma unroll
    for (int b = 0; b < 4; ++b) acc[a][b] = z4;

  for (int kc = 0; kc < 4; ++kc) {
    if (kc) __syncthreads();
    {
      int c4 = tid & 7, r0 = tid >> 3;
#pragma unroll
      for (int i = 0; i < 4; ++i) {
        int r = r0 + i * 32;
        int gr = rbase + r;
        float4 v = {0.f, 0.f, 0.f, 0.f};
        if (gr < NN) v = *(const float4*)(z + (long)gr * 128 + kc * 32 + c4 * 4);
        ushort4 h4, l4;
        split_bf(v.x, h4.x, l4.x); split_bf(v.y, h4.y, l4.y);
        split_bf(v.z, h4.z, l4.z); split_bf(v.w, h4.w, l4.w);
        *(ushort4*)(Ahi + r * 36 + c4 * 4) = h4;
        *(ushort4*)(Alo + r * 36 + c4 * 4) = l4;
      }
      int u = tid & 3, r0b = tid >> 2;
#pragma unroll
      for (int i = 0; i < 2; ++i) {
        int r = r0b + i * 64;
        uint4 vh = *(const uint4*)(w1h + ((cb * 128 + r) * 128 + kc * 32 + u * 8));
        uint4 vl = *(const uint4*)(w1l + ((cb * 128 + r) * 128 + kc * 32 + u * 8));
        *(uint4*)(Bhi + r * 36 + u * 8) = vh;
        *(uint4*)(Blo + r * 36 + u * 8) = vl;
      }
    }
    __syncthreads();
    bf16x8 ah[4], al[4], bh[4], bl[4];
#pragma unroll
    for (int rt = 0; rt < 4; ++rt) {
      ah[rt] = *(const bf16x8*)(Ahi + (wr * 64 + rt * 16 + m) * 36 + q * 8);
      al[rt] = *(const bf16x8*)(Alo + (wr * 64 + rt * 16 + m) * 36 + q * 8);
    }
#pragma unroll
    for (int ct = 0; ct < 4; ++ct) {
      bh[ct] = *(const bf16x8*)(Bhi + (wc * 64 + ct * 16 + m) * 36 + q * 8);
      bl[ct] = *(const bf16x8*)(Blo + (wc * 64 + ct * 16 + m) * 36 + q * 8);
    }
#pragma unroll
    for (int rt = 0; rt < 4; ++rt)
#pragma unroll
      for (int ct = 0; ct < 4; ++ct) {
        acc[rt][ct] = __builtin_amdgcn_mfma_f32_16x16x32_bf16(ah[rt], bh[ct], acc[rt][ct], 0, 0, 0);
        acc[rt][ct] = __builtin_amdgcn_mfma_f32_16x16x32_bf16(al[rt], bh[ct], acc[rt][ct], 0, 0, 0);
        acc[rt][ct] = __builtin_amdgcn_mfma_f32_16x16x32_bf16(ah[rt], bl[ct], acc[rt][ct], 0, 0, 0);
      }
  }
#pragma unroll
  for (int ct = 0; ct < 4; ++ct) {
    int gc = cb * 128 + wc * 64 + ct * 16 + m;
    float s = 0.f, s2 = 0.f;
#pragma unroll
    for (int rt = 0; rt < 4; ++rt) {
      int grow = rbase + wr * 64 + rt * 16 + q * 4;
#pragma unroll
      for (int i = 0; i < 4; ++i) {
        float v = acc[rt][ct][i];
        s += v; s2 += v * v;
        if (grow + i < NN) t1b[(long)(grow + i) * 256 + gc] = f2bf(v);
      }
    }
    s  += __shfl_xor(s, 16);  s  += __shfl_xor(s, 32);
    s2 += __shfl_xor(s2, 16); s2 += __shfl_xor(s2, 32);
    if (q == 0) { unsafeAtomicAdd(&sum1[gc], s); unsafeAtomicAdd(&sq1[gc], s2); }
  }
}

// ---------------- stats: scale = g*rsqrt(var+eps), shift = bt - mu*scale
__global__ void stats_kernel(const float* __restrict__ sum, const float* __restrict__ sq,
                             const float* __restrict__ g, const float* __restrict__ bt,
                             float* __restrict__ scale, float* __restrict__ shift, int C) {
  int j = blockIdx.x * blockDim.x + threadIdx.x;
  if (j >= C) return;
  float mu = sum[j] * (1.f / NN);
  float var = sq[j] * (1.f / NN) - mu * mu;
  var = fmaxf(var, 0.f);
  float is = rsqrtf(var + 1e-5f);
  float sc = g[j] * is;
  scale[j] = sc;
  shift[j] = bt[j] - mu * sc;
}

// ---------------- GEMM2: t2 = relu(BN1(t1)) @ W2 (split-bf16); t1 bf16 (N,256); out t2 f32 (N,128) + stats
// t2 (f32) overlays t1b (bf16) — same 512B/row extent; safe (reads precede writes per block).
__global__ __launch_bounds__(256) void gemm2_kernel(const unsigned short* t1b,
                                                    const float* __restrict__ scale1,
                                                    const float* __restrict__ shift1,
                                                    const unsigned short* __restrict__ w2h,
                                                    const unsigned short* __restrict__ w2l,
                                                    float* t2,
                                                    float* __restrict__ sum2,
                                                    float* __restrict__ sq2) {
  __shared__ unsigned short Ahi[128 * 36];
  __shared__ unsigned short Alo[128 * 36];
  __shared__ unsigned short Bhi[128 * 36];
  __shared__ unsigned short Blo[128 * 36];
  const int tid = threadIdx.x;
  const int rbase = blockIdx.x * 128;
  const int w = tid >> 6, lane = tid & 63;
  const int wr = w >> 1, wc = w & 1;
  const int m = lane & 15, q = lane >> 4;
  f32x4 acc[4][4];
  const f32x4 z4 = {0.f, 0.f, 0.f, 0.f};
#pragma unroll
  for (int a = 0; a < 4; ++a)
#pragma unroll
    for (int b = 0; b < 4; ++b) acc[a][b] = z4;

  for (int kc = 0; kc < 8; ++kc) {
    if (kc) __syncthreads();
    {
      int u4 = tid & 3, r0 = tid >> 2;
      int j0 = kc * 32 + u4 * 8;
      float4 sc0 = *(const float4*)(scale1 + j0);
      float4 sc1 = *(const float4*)(scale1 + j0 + 4);
      float4 sh0 = *(const float4*)(shift1 + j0);
      float4 sh1 = *(const float4*)(shift1 + j0 + 4);
#pragma unroll
      for (int i = 0; i < 2; ++i) {
        int r = r0 + i * 64;
        int gr = rbase + r;
        ushort4 h0 = {0, 0, 0, 0}, l0 = {0, 0, 0, 0};
        ushort4 h1 = {0, 0, 0, 0}, l1 = {0, 0, 0, 0};
        if (gr < NN) {
          const unsigned short* srcp = t1b + (long)gr * 256 + j0;
          ushort4 u0 = *(const ushort4*)(srcp);
          ushort4 u1 = *(const ushort4*)(srcp + 4);
          float a0 = fmaxf(bf2f(u0.x) * sc0.x + sh0.x, 0.f);
          float a1 = fmaxf(bf2f(u0.y) * sc0.y + sh0.y, 0.f);
          float a2 = fmaxf(bf2f(u0.z) * sc0.z + sh0.z, 0.f);
          float a3 = fmaxf(bf2f(u0.w) * sc0.w + sh0.w, 0.f);
          float a4 = fmaxf(bf2f(u1.x) * sc1.x + sh1.x, 0.f);
          float a5 = fmaxf(bf2f(u1.y) * sc1.y + sh1.y, 0.f);
          float a6 = fmaxf(bf2f(u1.z) * sc1.z + sh1.z, 0.f);
          float a7 = fmaxf(bf2f(u1.w) * sc1.w + sh1.w, 0.f);
          split_bf(a0, h0.x, l0.x); split_bf(a1, h0.y, l0.y);
          split_bf(a2, h0.z, l0.z); split_bf(a3, h0.w, l0.w);
          split_bf(a4, h1.x, l1.x); split_bf(a5, h1.y, l1.y);
          split_bf(a6, h1.z, l1.z); split_bf(a7, h1.w, l1.w);
        }
        *(ushort4*)(Ahi + r * 36 + u4 * 8) = h0;
        *(ushort4*)(Ahi + r * 36 + u4 * 8 + 4) = h1;
        *(ushort4*)(Alo + r * 36 + u4 * 8) = l0;
        *(ushort4*)(Alo + r * 36 + u4 * 8 + 4) = l1;
      }
      int u = tid & 3, r0b = tid >> 2;
#pragma unroll
      for (int i = 0; i < 2; ++i) {
        int r = r0b + i * 64;
        uint4 vh = *(const uint4*)(w2h + (r * 256 + kc * 32 + u * 8));
        uint4 vl = *(const uint4*)(w2l + (r * 256 + kc * 32 + u * 8));
        *(uint4*)(Bhi + r * 36 + u * 8) = vh;
        *(uint4*)(Blo + r * 36 + u * 8) = vl;
      }
    }
    __syncthreads();
    bf16x8 ah[4], al[4], bh[4], bl[4];
#pragma unroll
    for (int rt = 0; rt < 4; ++rt) {
      ah[rt] = *(const bf16x8*)(Ahi + (wr * 64 + rt * 16 + m) * 36 + q * 8);
      al[rt] = *(const bf16x8*)(Alo + (wr * 64 + rt * 16 + m) * 36 + q * 8);
    }
#pragma unroll
    for (int ct = 0; ct < 4; ++ct) {
      bh[ct] = *(const bf16x8*)(Bhi + (wc * 64 + ct * 16 + m) * 36 + q * 8);
      bl[ct] = *(const bf16x8*)(Blo + (wc * 64 + ct * 16 + m) * 36 + q * 8);
    }
#pragma unroll
    for (int rt = 0; rt < 4; ++rt)
#pragma unroll
      for (int ct = 0; ct < 4; ++ct) {
        acc[rt][ct] = __builtin_amdgcn_mfma_f32_16x16x32_bf16(ah[rt], bh[ct], acc[rt][ct], 0, 0, 0);
        acc[rt][ct] = __builtin_amdgcn_mfma_f32_16x16x32_bf16(al[rt], bh[ct], acc[rt][ct], 0, 0, 0);
        acc[rt][ct] = __builtin_amdgcn_mfma_f32_16x16x32_bf16(ah[rt], bl[ct], acc[rt][ct], 0, 0, 0);
      }
  }
#pragma unroll
  for (int ct = 0; ct < 4; ++ct) {
    int gc = wc * 64 + ct * 16 + m;
    float s = 0.f, s2 = 0.f;
#pragma unroll
    for (int rt = 0; rt < 4; ++rt) {
      int grow = rbase + wr * 64 + rt * 16 + q * 4;
#pragma unroll
      for (int i = 0; i < 4; ++i) {
        float v = acc[rt][ct][i];
        s += v; s2 += v * v;
        if (grow + i < NN) t2[(long)(grow + i) * 128 + gc] = v;
      }
    }
    s  += __shfl_xor(s, 16);  s  += __shfl_xor(s, 32);
    s2 += __shfl_xor(s2, 16); s2 += __shfl_xor(s2, 32);
    if (q == 0) { unsafeAtomicAdd(&sum2[gc], s); unsafeAtomicAdd(&sq2[gc], s2); }
  }
}

// ---------------- apply: y = BN2(t2); h = relu(y) (or y if last)
__global__ __launch_bounds__(256) void apply_kernel(const float* __restrict__ t2,
                                                    const float* __restrict__ scale2,
                                                    const float* __restrict__ shift2,
                                                    int last,
                                                    float* __restrict__ h) {
  int gid = blockIdx.x * 256 + threadIdx.x;
  int n = gid >> 5, qq = gid & 31;
  if (n >= NN) return;
  float4 u = *(const float4*)(t2 + (long)n * 128 + qq * 4);
  float4 sc = *(const float4*)(scale2 + qq * 4);
  float4 sh = *(const float4*)(shift2 + qq * 4);
  float4 y;
  y.x = u.x * sc.x + sh.x;
  y.y = u.y * sc.y + sh.y;
  y.z = u.z * sc.z + sh.z;
  y.w = u.w * sc.w + sh.w;
  if (!last) {
    y.x = fmaxf(y.x, 0.f); y.y = fmaxf(y.y, 0.f);
    y.z = fmaxf(y.z, 0.f); y.w = fmaxf(y.w, 0.f);
  }
  *(float4*)(h + (long)n * 128 + qq * 4) = y;
}

extern "C" void kernel_launch(void* const* d_in, const int* in_sizes, int n_in,
                              void* d_out, int out_size, void* d_ws, size_t ws_size,
                              hipStream_t stream) {
  (void)in_sizes; (void)n_in; (void)out_size; (void)ws_size;
  const int*   x      = (const int*)d_in[0];
  const int*   ei     = (const int*)d_in[1];
  const int*   ea     = (const int*)d_in[2];
  const float* ew     = (const float*)d_in[3];
  const float* aemb   = (const float*)d_in[4];
  const float* bemb   = (const float*)d_in[5];
  const float* eps    = (const float*)d_in[6];
  const float* W1     = (const float*)d_in[7];
  const float* g1     = (const float*)d_in[9];
  const float* bt1    = (const float*)d_in[10];
  const float* W2     = (const float*)d_in[11];
  const float* g_out  = (const float*)d_in[13];
  const float* bt_out = (const float*)d_in[14];

  float* h = (float*)d_out; // (N,128) f32

  // ws layout (total ~108.9 MB):
  char* ws = (char*)d_ws;
  float*          agg = (float*)(ws);                        // 51,200,000
  unsigned short* t1b = (unsigned short*)(ws + 51200000);    // (N,256) bf16, overlaid by t2 f32
  float*          t2  = (float*)(ws + 51200000);
  unsigned short* w1h = (unsigned short*)(ws + 102400000);
  unsigned short* w1l = (unsigned short*)(ws + 102727680);
  unsigned short* w2h = (unsigned short*)(ws + 103055360);
  unsigned short* w2l = (unsigned short*)(ws + 103383040);
  float* stats = (float*)(ws + 103710720);                   // 1536 f32 -> ends 103,716,864
  int*   deg    = (int*)(ws + 103716864);                    // 100000 ints
  int*   offs   = (int*)(ws + 104116864);                    // 100001 ints
  int*   cursor = (int*)(ws + 104516880);                    // 100000 ints
  int*   bsum   = (int*)(ws + 104916880);                    // 98 ints (pad 400)
  int*   pk     = (int*)(ws + 104917280);                    // 500000 ints
  float* wsrt   = (float*)(ws + 106917280);                  // 500000 f32 -> ends 108,917,280

  float* sum1 = stats;          float* sq1 = stats + 256;
  float* scale1 = stats + 512;  float* shift1 = stats + 768;
  float* sum2 = stats + 1024;   float* sq2 = stats + 1152;
  float* scale2 = stats + 1280; float* shift2 = stats + 1408;

  // one-time per launch: weight prep + CSR build + atom embedding
  prep_kernel<<<1280, 256, 0, stream>>>(W1, W2, w1h, w1l, w2h, w2l);
  zero_deg_kernel<<<391, 256, 0, stream>>>(deg);
  hist_kernel<<<1954, 256, 0, stream>>>(ei, deg);
  scan1_kernel<<<98, 256, 0, stream>>>(deg, offs, bsum);
  scan2_kernel<<<1, 64, 0, stream>>>(bsum, 98);
  scan3_kernel<<<392, 256, 0, stream>>>(offs, bsum, cursor);
  scatter_kernel<<<1954, 256, 0, stream>>>(ei, ea, ew, cursor, pk, wsrt);
  atom_kernel<<<12500, 256, 0, stream>>>(x, aemb, h);

  for (int l = 0; l < 5; ++l) {
    zero_kernel<<<1, 256, 0, stream>>>(stats);
    edge_agg_kernel<<<12500, 256, 0, stream>>>(offs, pk, wsrt, bemb + l * 3072, eps, l, h, agg);
    gemm1_kernel<<<dim3(782, 2), 256, 0, stream>>>(agg, w1h + l * 32768, w1l + l * 32768, t1b, sum1, sq1);
    stats_kernel<<<1, 256, 0, stream>>>(sum1, sq1, g1 + l * 256, bt1 + l * 256, scale1, shift1, 256);
    gemm2_kernel<<<782, 256, 0, stream>>>(t1b, scale1, shift1, w2h + l * 32768, w2l + l * 32768, t2, sum2, sq2);
    stats_kernel<<<1, 128, 0, stream>>>(sum2, sq2, g_out + l * 128, bt_out + l * 128, scale2, shift2, 128);
    apply_kernel<<<12500, 256, 0, stream>>>(t2, scale2, shift2, (l == 4) ? 1 : 0, h);
  }
}